// Round 20
// baseline (1579.544 us; speedup 1.0000x reference)
//
#include <hip/hip_runtime.h>
#include <hip/hip_bf16.h>
#include <math.h>

#define B 32
#define S 512
#define W 8
#define CE 100       // CHAR_EMB
#define SE 100       // SUB_EMB
#define HD 200       // hidden per direction
#define G4 800       // 4*HD
#define IN2 200      // 2*CHAR_EMB
#define SUBV 100000
#define UNK 1
#define NL 4
#define SK (S - 2)   // 510
#define FEAT 500     // 2*HD + SE

typedef _Float16 h2_t __attribute__((ext_vector_type(2)));

__device__ __forceinline__ float fsig(float x) {
    return 1.f / (1.f + __expf(-x));
}
__device__ __forceinline__ float ftanh(float x) {
    float e = __expf(-2.f * fabsf(x));   // e in (0,1], overflow-safe
    float r = (1.f - e) / (1.f + e);
    return copysignf(r, x);
}

// 64-lane sum; result valid in lane 63. DPP adds run on the VALU pipe.
__device__ __forceinline__ float wave_sum64(float v) {
#if __has_builtin(__builtin_amdgcn_update_dpp)
#define DPPADD(C) { int x_ = __builtin_amdgcn_update_dpp(0, __float_as_int(v), C, 0xf, 0xf, true); \
                    v += __int_as_float(x_); }
    DPPADD(0x111)  // row_shr:1
    DPPADD(0x112)  // row_shr:2
    DPPADD(0x114)  // row_shr:4
    DPPADD(0x118)  // row_shr:8  -> lane15/31/47/63 hold row sums
    DPPADD(0x142)  // row_bcast15 -> lane31 = rows0+1, lane63 = rows2+3
    DPPADD(0x143)  // row_bcast31 -> lane63 = total
#undef DPPADD
    return v;
#else
    v += __shfl_xor(v, 1);  v += __shfl_xor(v, 2);  v += __shfl_xor(v, 4);
    v += __shfl_xor(v, 8);  v += __shfl_xor(v, 16); v += __shfl_xor(v, 32);
    return v;
#endif
}

__device__ __forceinline__ float dot4(float4 w, float4 h) {
    return fmaf(w.w, h.w, fmaf(w.z, h.z, fmaf(w.y, h.y, w.x * h.x)));
}

// packed-f16 2-way dot with f32 accumulate (v_dot2_f32_f16)
__device__ __forceinline__ float dot2f(unsigned a, unsigned b, float c) {
#if __has_builtin(__builtin_amdgcn_fdot2)
    return __builtin_amdgcn_fdot2(__builtin_bit_cast(h2_t, a),
                                  __builtin_bit_cast(h2_t, b), c, false);
#else
    h2_t x = __builtin_bit_cast(h2_t, a);
    h2_t y = __builtin_bit_cast(h2_t, b);
    return c + (float)x[0] * (float)y[0] + (float)x[1] * (float)y[1];
#endif
}

// ------- K0: transpose + pack f16: Wih[800][200] -> WTh[100][800] u32 ----
__global__ void transpose_pack_k(const float* __restrict__ in, unsigned* __restrict__ out) {
    int o = blockIdx.x * 256 + threadIdx.x;   // 80000 elements
    if (o >= 100 * G4) return;
    int k2 = o / G4, g = o % G4;
    h2_t v;
    v[0] = (_Float16)in[g * 200 + 2 * k2];
    v[1] = (_Float16)in[g * 200 + 2 * k2 + 1];
    out[o] = __builtin_bit_cast(unsigned, v);
}

// ---------------- K2: fused embed + xg via v_dot2_f32_f16 ----------------
__global__ void xg_k(const int* __restrict__ chars, const int* __restrict__ bichars,
                     const float* __restrict__ cw, const float* __restrict__ bw,
                     const unsigned* __restrict__ WTh_f, const float* __restrict__ bf,
                     const unsigned* __restrict__ WTh_b, const float* __restrict__ bb,
                     float* __restrict__ xgf, float* __restrict__ xgb) {
    const int dir = blockIdx.y;
    const unsigned* WT = dir ? WTh_b : WTh_f;
    const float* bias  = dir ? bb : bf;
    float* out         = dir ? xgb : xgf;
    int r0 = blockIdx.x * 16;
    __shared__ unsigned xs2[16][100];
    for (int i = threadIdx.x; i < 16 * 100; i += 256) {
        int r = i / 100, c2 = i % 100;
        int row = r0 + r;                         // flat token index b*S+s
        float a, b;
        if (c2 < 50) {
            const float* p = cw + (size_t)chars[row] * CE + 2 * c2;
            a = p[0]; b = p[1];
        } else {
            const float* p = bw + (size_t)bichars[row] * CE + 2 * (c2 - 50);
            a = p[0]; b = p[1];
        }
        h2_t v; v[0] = (_Float16)a; v[1] = (_Float16)b;
        xs2[r][c2] = __builtin_bit_cast(unsigned, v);
    }
    __syncthreads();
    float acc[4][16];
    for (int q = 0; q < 4; q++)
        for (int r = 0; r < 16; r++) acc[q][r] = 0.f;
    int tid = threadIdx.x;
    for (int k2 = 0; k2 < 100; k2++) {
        const unsigned* wrow = WT + (size_t)k2 * G4;
        unsigned w0 = wrow[tid];
        unsigned w1 = wrow[tid + 256];
        unsigned w2 = wrow[tid + 512];
        unsigned w3 = (tid < 32) ? wrow[tid + 768] : 0u;
        for (int r = 0; r < 16; r++) {
            unsigned xv = xs2[r][k2];
            acc[0][r] = dot2f(w0, xv, acc[0][r]);
            acc[1][r] = dot2f(w1, xv, acc[1][r]);
            acc[2][r] = dot2f(w2, xv, acc[2][r]);
            acc[3][r] = dot2f(w3, xv, acc[3][r]);
        }
    }
    for (int q = 0; q < 4; q++) {
        int g = tid + q * 256;
        if (g < G4) {
            float bv = bias[g];
            for (int r = 0; r < 16; r++)
                out[(size_t)(r0 + r) * G4 + g] = acc[q][r] + bv;
        }
    }
}

// ---------------- K3: LSTM recurrence, shared-weight dual-chain ----------
// grid = 256 blocks = 8 slices x (2 dirs x 16 pairs); blk = sl*32 + pg keeps
// all 8 slices of a pair-chain on one XCD. T=1024. NEW: per step, 2 phases:
//  Phase1(s): wave15 acts A(s-1), wave14 acts B(s-1) (parallel; gb from
//    phase2(s-1)); waves 0-3 poll-fill foreign h_A(s-1) -> hsA; waves 4-7
//    fill h_B(s-1) -> hsB. Rendezvous is exposed (~1 L2/L3 round trip) but
//    act waves NEVER poll -> progress guaranteed (write-once NaN protocol).
//  Phase2(s): ALL 16 waves compute BOTH chains with SHARED weight reads:
//    one ds_read_b128 of wv serves dot4(wv,hvA) and dot4(wv,hvB) + two
//    interleaved DPP reductions. Weight LDS traffic per step halves
//    (210 -> 100 b128) vs the r13 schedule.
// hout NaN-filled per launch; all over-readable LDS zero-filled (r15).
__global__ __launch_bounds__(1024)
void lstm_k(const float* __restrict__ xgf, const float* __restrict__ xgb,
            const float* __restrict__ Whh_f, const float* __restrict__ Whh_b,
            float* __restrict__ hf, float* __restrict__ hb) {
    __shared__ float4 wlds[5064];                 // [col*50+l]; zero-padded tail
    __shared__ __align__(16) float hsA[256];
    __shared__ __align__(16) float hsB[256];
    __shared__ __align__(16) float gbA[112];      // [gate*25 + unit]
    __shared__ __align__(16) float gbB[112];

    const int blk = blockIdx.x;
    const int sl  = blk >> 5;                     // slice 0..7 (25 units)
    const int pg  = blk & 31;                     // dir*16 + pair; XCD = pg%8
    const int dir = pg >> 4;
    const int bA  = pg & 15;
    const int bB  = bA + 16;
    const float* xg  = dir ? xgb : xgf;
    const float* Whh = dir ? Whh_b : Whh_f;
    float* hout      = dir ? hb : hf;

    const int t = threadIdx.x;
    const int lane = t & 63;
    const int wid = t >> 6;                       // wave id 0..15

    // stage weights: wlds[col*50+l] = Whh[row(col)][4l..4l+3]
    // col = gate*25+unit -> row = gate*200 + sl*25 + unit.
    // Slots [5000,5064): ZEROED (lane>=50 over-reads must be finite — r15).
    for (int i = t; i < 5064; i += 1024) {
        float4 v = {0.f, 0.f, 0.f, 0.f};
        if (i < 5000) {
            int col = i / 50, l = i - col * 50;
            int row = (col / 25) * 200 + sl * 25 + (col % 25);
            v = *(const float4*)(Whh + (size_t)row * HD + 4 * l);
        }
        wlds[i] = v;
    }
    if (t < 256) { hsA[t] = 0.f; hsB[t] = 0.f; }

    const bool actA = (t >= 960) && (t < 985);    // wave 15, lanes 0..24
    const bool actB = (t >= 896) && (t < 921);    // wave 14, lanes 0..24
    const int u = actA ? (t - 960) : (t - 896);
    const bool fillA = (t < 200) && (t / 25 != sl);
    const int tB = t - 256;
    const bool fillB = (t >= 256) && (tB < 200) && (tB / 25 != sl);
    float cst = 0.f;                              // A-state in w15, B in w14
    float x0 = 0, x1 = 0, x2 = 0, x3 = 0;
    if (actA || actB) {
        int ts0 = dir ? (S - 1) : 0;
        int bX = actA ? bA : bB;
        const float* p = xg + ((size_t)bX * S + ts0) * G4 + sl * 25 + u;
        x0 = p[0]; x1 = p[200]; x2 = p[400]; x3 = p[600];
    }
    __syncthreads();

#define POLL(dst, srcp)                                                        \
    {                                                                          \
        float v_;                                                              \
        do { v_ = __hip_atomic_load(srcp, __ATOMIC_RELAXED,                    \
                                    __HIP_MEMORY_SCOPE_AGENT); } while (v_ != v_); \
        dst = v_;                                                              \
    }

    for (int s = 0; s < S; s++) {
        const int ts  = dir ? (S - 1 - s) : s;          // time of step s
        const int tsp = dir ? (S - s)     : (s - 1);    // time of step s-1

        // ==== Phase1: act A(s-1)[w15] | act B(s-1)[w14] | fills (waves 0-7)
        if (s > 0) {
            if (actA || actB) {
                const float* gb = actA ? gbA : gbB;
                float* hsX = actA ? hsA : hsB;
                const int bX = actA ? bA : bB;
                float ig = fsig(gb[u] + x0);
                float fg = fsig(gb[25 + u] + x1);
                float gt = ftanh(gb[50 + u] + x2);
                float og = fsig(gb[75 + u] + x3);
                cst = fg * cst + ig * gt;
                float h = og * ftanh(cst);
                hsX[sl * 25 + u] = h;
                __hip_atomic_store(&hout[((size_t)bX * S + tsp) * HD + sl * 25 + u],
                                   h, __ATOMIC_RELAXED, __HIP_MEMORY_SCOPE_AGENT);
                const float* pn = xg + ((size_t)bX * S + ts) * G4 + sl * 25 + u;
                x0 = pn[0]; x1 = pn[200]; x2 = pn[400]; x3 = pn[600];
            }
            if (fillA) POLL(hsA[t],  hout + ((size_t)bA * S + tsp) * HD + t)
            if (fillB) POLL(hsB[tB], hout + ((size_t)bB * S + tsp) * HD + tB)
        }
        __syncthreads();

        // ==== Phase2: all 16 waves compute BOTH chains, shared wv reads ====
        {
            float4 hvA = ((const float4*)hsA)[lane];
            float4 hvB = ((const float4*)hsB)[lane];
            #pragma unroll
            for (int j = 0; j < 7; j++) {
                int c = wid + 16 * j;
                if (c < 100) {
                    float4 wv = wlds[c * 50 + lane];
                    float a = wave_sum64(dot4(wv, hvA));
                    float b = wave_sum64(dot4(wv, hvB));
                    if (lane == 63) { gbA[c] = a; gbB[c] = b; }
                }
            }
        }
        __syncthreads();
    }
    // epilogue: act A(S-1) and B(S-1) (gb from final phase2; x prefetched)
    if (actA || actB) {
        const float* gb = actA ? gbA : gbB;
        const int bX = actA ? bA : bB;
        const int tl = dir ? 0 : (S - 1);
        float ig = fsig(gb[u] + x0);
        float fg = fsig(gb[25 + u] + x1);
        float gt = ftanh(gb[50 + u] + x2);
        float og = fsig(gb[75 + u] + x3);
        cst = fg * cst + ig * gt;
        float h = og * ftanh(cst);
        __hip_atomic_store(&hout[((size_t)bX * S + tl) * HD + sl * 25 + u], h,
                           __ATOMIC_RELAXED, __HIP_MEMORY_SCOPE_AGENT);
    }
#undef POLL
}

// ---------------- K4: span features + subword emb + FFN ----------------
__global__ void out_k(const int* __restrict__ subwords,
                      const float* __restrict__ pre_w, const float* __restrict__ sub_w,
                      const float* __restrict__ hf, const float* __restrict__ hb,
                      const float* __restrict__ ffn_w, const float* __restrict__ ffn_b,
                      float* __restrict__ out) {
    int wave = (blockIdx.x * 256 + threadIdx.x) >> 6;
    int lane = threadIdx.x & 63;
    if (wave >= B * SK * W) return;
    int i = wave % W;
    int bk = wave / W;
    int k = bk % SK;
    int b = bk / SK;
    int end = k + i;
    float vscale = (end <= S - 3) ? 1.f : 0.f;
    int e1 = min(end + 1, S - 1);
    int e2 = min(end + 2, S - 1);
    const float* hfb = hf + (size_t)b * S * HD;
    const float* hbb = hb + (size_t)b * S * HD;
    int sw = subwords[wave];
    int sw2 = (sw >= SUBV) ? UNK : sw;
    float acc0 = 0, acc1 = 0, acc2 = 0, acc3 = 0;
    for (int j = lane; j < FEAT; j += 64) {
        float fv;
        if (j < HD) {
            fv = (hfb[(size_t)e1 * HD + j] - hfb[(size_t)k * HD + j]) * vscale;
        } else if (j < 2 * HD) {
            int jj = j - HD;
            fv = (hbb[(size_t)(k + 1) * HD + jj] - hbb[(size_t)e2 * HD + jj]) * vscale;
        } else {
            int jj = j - 2 * HD;
            fv = pre_w[(size_t)sw * SE + jj] + sub_w[(size_t)sw2 * SE + jj];
        }
        acc0 += ffn_w[j] * fv;
        acc1 += ffn_w[FEAT + j] * fv;
        acc2 += ffn_w[2 * FEAT + j] * fv;
        acc3 += ffn_w[3 * FEAT + j] * fv;
    }
    for (int off = 32; off; off >>= 1) {
        acc0 += __shfl_down(acc0, off);
        acc1 += __shfl_down(acc1, off);
        acc2 += __shfl_down(acc2, off);
        acc3 += __shfl_down(acc3, off);
    }
    if (lane == 0) {
        float* o = out + (size_t)wave * NL;
        o[0] = acc0 + ffn_b[0];
        o[1] = acc1 + ffn_b[1];
        o[2] = acc2 + ffn_b[2];
        o[3] = acc3 + ffn_b[3];
    }
}

extern "C" void kernel_launch(void* const* d_in, const int* in_sizes, int n_in,
                              void* d_out, int out_size, void* d_ws, size_t ws_size,
                              hipStream_t stream) {
    const int*   chars    = (const int*)d_in[0];
    const int*   bichars  = (const int*)d_in[1];
    const int*   subwords = (const int*)d_in[2];
    const float* cw    = (const float*)d_in[3];
    const float* bw    = (const float*)d_in[4];
    const float* subw  = (const float*)d_in[5];
    const float* prew  = (const float*)d_in[6];
    const float* Wih_f = (const float*)d_in[7];
    const float* Whh_f = (const float*)d_in[8];
    const float* b_f   = (const float*)d_in[9];
    const float* Wih_b = (const float*)d_in[10];
    const float* Whh_b = (const float*)d_in[11];
    const float* b_b   = (const float*)d_in[12];
    const float* ffn_w = (const float*)d_in[13];
    const float* ffn_b = (const float*)d_in[14];
    float* out = (float*)d_out;

    float* ws = (float*)d_ws;
    unsigned* WTh_f = (unsigned*)ws;         // 80000 u32 each (packed f16)
    unsigned* WTh_b = WTh_f + 80000;
    float* xgf = (float*)(WTh_b + 80000);    // 13,107,200
    float* xgb = xgf + 13107200;             // 13,107,200
    float* hf  = xgb + 13107200;             // 3,276,800
    float* hb  = hf + 3276800;               // 3,276,800 (contiguous with hf)

    // NaN-fill h buffers (one fused memset: hf|hb contiguous) — the data
    // word itself is the readiness flag for the lstm spin-sync.
    (void)hipMemsetAsync(hf, 0xFF, 2 * 3276800 * sizeof(float), stream);
    transpose_pack_k<<<313, 256, 0, stream>>>(Wih_f, WTh_f);
    transpose_pack_k<<<313, 256, 0, stream>>>(Wih_b, WTh_b);
    xg_k<<<dim3(B * S / 16, 2), 256, 0, stream>>>(chars, bichars, cw, bw,
                                                  WTh_f, b_f, WTh_b, b_b, xgf, xgb);
    lstm_k<<<256, 1024, 0, stream>>>(xgf, xgb, Whh_f, Whh_b, hf, hb);
    out_k<<<(B * SK * W) / 4, 256, 0, stream>>>(subwords, prew, subw, hf, hb, ffn_w, ffn_b, out);
}

// Round 21
// 1161.047 us; speedup vs baseline: 1.3604x; 1.3604x over previous
//
#include <hip/hip_runtime.h>
#include <hip/hip_bf16.h>
#include <math.h>

#define B 32
#define S 512
#define W 8
#define CE 100       // CHAR_EMB
#define SE 100       // SUB_EMB
#define HD 200       // hidden per direction
#define G4 800       // 4*HD
#define IN2 200      // 2*CHAR_EMB
#define SUBV 100000
#define UNK 1
#define NL 4
#define SK (S - 2)   // 510
#define FEAT 500     // 2*HD + SE

typedef _Float16 h2_t __attribute__((ext_vector_type(2)));

__device__ __forceinline__ float fsig(float x) {
    return 1.f / (1.f + __expf(-x));
}
__device__ __forceinline__ float ftanh(float x) {
    float e = __expf(-2.f * fabsf(x));   // e in (0,1], overflow-safe
    float r = (1.f - e) / (1.f + e);
    return copysignf(r, x);
}

// 64-lane sum; result valid in lane 63. DPP adds run on the VALU pipe.
__device__ __forceinline__ float wave_sum64(float v) {
#if __has_builtin(__builtin_amdgcn_update_dpp)
#define DPPADD(C) { int x_ = __builtin_amdgcn_update_dpp(0, __float_as_int(v), C, 0xf, 0xf, true); \
                    v += __int_as_float(x_); }
    DPPADD(0x111)  // row_shr:1
    DPPADD(0x112)  // row_shr:2
    DPPADD(0x114)  // row_shr:4
    DPPADD(0x118)  // row_shr:8  -> lane15/31/47/63 hold row sums
    DPPADD(0x142)  // row_bcast15 -> lane31 = rows0+1, lane63 = rows2+3
    DPPADD(0x143)  // row_bcast31 -> lane63 = total
#undef DPPADD
    return v;
#else
    v += __shfl_xor(v, 1);  v += __shfl_xor(v, 2);  v += __shfl_xor(v, 4);
    v += __shfl_xor(v, 8);  v += __shfl_xor(v, 16); v += __shfl_xor(v, 32);
    return v;
#endif
}

// packed-f16 2-way dot with f32 accumulate (v_dot2_f32_f16)
__device__ __forceinline__ float dot2f(unsigned a, unsigned b, float c) {
#if __has_builtin(__builtin_amdgcn_fdot2)
    return __builtin_amdgcn_fdot2(__builtin_bit_cast(h2_t, a),
                                  __builtin_bit_cast(h2_t, b), c, false);
#else
    h2_t x = __builtin_bit_cast(h2_t, a);
    h2_t y = __builtin_bit_cast(h2_t, b);
    return c + (float)x[0] * (float)y[0] + (float)x[1] * (float)y[1];
#endif
}

// ------- K0: transpose + pack f16: Wih[800][200] -> WTh[100][800] u32 ----
__global__ void transpose_pack_k(const float* __restrict__ in, unsigned* __restrict__ out) {
    int o = blockIdx.x * 256 + threadIdx.x;   // 80000 elements
    if (o >= 100 * G4) return;
    int k2 = o / G4, g = o % G4;
    h2_t v;
    v[0] = (_Float16)in[g * 200 + 2 * k2];
    v[1] = (_Float16)in[g * 200 + 2 * k2 + 1];
    out[o] = __builtin_bit_cast(unsigned, v);
}

// ---------------- K2: fused embed + xg via v_dot2_f32_f16 ----------------
__global__ void xg_k(const int* __restrict__ chars, const int* __restrict__ bichars,
                     const float* __restrict__ cw, const float* __restrict__ bw,
                     const unsigned* __restrict__ WTh_f, const float* __restrict__ bf,
                     const unsigned* __restrict__ WTh_b, const float* __restrict__ bb,
                     float* __restrict__ xgf, float* __restrict__ xgb) {
    const int dir = blockIdx.y;
    const unsigned* WT = dir ? WTh_b : WTh_f;
    const float* bias  = dir ? bb : bf;
    float* out         = dir ? xgb : xgf;
    int r0 = blockIdx.x * 16;
    __shared__ unsigned xs2[16][100];
    for (int i = threadIdx.x; i < 16 * 100; i += 256) {
        int r = i / 100, c2 = i % 100;
        int row = r0 + r;                         // flat token index b*S+s
        float a, b;
        if (c2 < 50) {
            const float* p = cw + (size_t)chars[row] * CE + 2 * c2;
            a = p[0]; b = p[1];
        } else {
            const float* p = bw + (size_t)bichars[row] * CE + 2 * (c2 - 50);
            a = p[0]; b = p[1];
        }
        h2_t v; v[0] = (_Float16)a; v[1] = (_Float16)b;
        xs2[r][c2] = __builtin_bit_cast(unsigned, v);
    }
    __syncthreads();
    float acc[4][16];
    for (int q = 0; q < 4; q++)
        for (int r = 0; r < 16; r++) acc[q][r] = 0.f;
    int tid = threadIdx.x;
    for (int k2 = 0; k2 < 100; k2++) {
        const unsigned* wrow = WT + (size_t)k2 * G4;
        unsigned w0 = wrow[tid];
        unsigned w1 = wrow[tid + 256];
        unsigned w2 = wrow[tid + 512];
        unsigned w3 = (tid < 32) ? wrow[tid + 768] : 0u;
        for (int r = 0; r < 16; r++) {
            unsigned xv = xs2[r][k2];
            acc[0][r] = dot2f(w0, xv, acc[0][r]);
            acc[1][r] = dot2f(w1, xv, acc[1][r]);
            acc[2][r] = dot2f(w2, xv, acc[2][r]);
            acc[3][r] = dot2f(w3, xv, acc[3][r]);
        }
    }
    for (int q = 0; q < 4; q++) {
        int g = tid + q * 256;
        if (g < G4) {
            float bv = bias[g];
            for (int r = 0; r < 16; r++)
                out[(size_t)(r0 + r) * G4 + g] = acc[q][r] + bv;
        }
    }
}

// ---------------- K3: LSTM recurrence, f16-packed weights + h ------------
// EXACT r13/r17 schedule (2 superphases/step, 1 barrier each: act-first ->
// compute -> fill-poll; staggered A/B so each chain's compute hides the
// other's act+fill). Change vs r17: Whh slice AND the h working copy live
// in LDS as packed f16. Per column: 1 ds_read_b64 + 2 v_dot2_f32_f16
// (f32 accumulate) — halves the LDS issue cost that bound r13 WITHOUT
// r16's unpack chain (bf16 has no dot2; f16 does). h stays f32 in hout
// (sync protocol / output path unchanged); act+fill write an f16 copy.
// All over-readable LDS zero-filled (r15); single genuinely-used 86KB LDS
// array pins 1 block/CU (r19 lesson; not DCE-able, r14 lesson).
__global__ __launch_bounds__(1024)
void lstm_k(const float* __restrict__ xgf, const float* __restrict__ xgb,
            const float* __restrict__ Whh_f, const float* __restrict__ Whh_b,
            float* __restrict__ hf, float* __restrict__ hb) {
    __shared__ __align__(16) float lds_all[21504];   // 86016 B -> 1 block/CU
    uint2*    wlds16 = (uint2*)lds_all;              // 5064 uint2 (f16x4 each)
    _Float16* h16A = (_Float16*)(lds_all + 10240);   // 256 f16 (512 B)
    _Float16* h16B = (_Float16*)(lds_all + 10368);   // 256 f16
    float*    gbA  = lds_all + 10496;                // 112 f32
    float*    gbB  = lds_all + 10608;                // 112 f32

    const int blk = blockIdx.x;
    const int sl  = blk >> 5;                     // slice 0..7 (25 units)
    const int pg  = blk & 31;                     // dir*16 + pair; XCD = pg%8
    const int dir = pg >> 4;
    const int bA  = pg & 15;
    const int bB  = bA + 16;
    const float* xg  = dir ? xgb : xgf;
    const float* Whh = dir ? Whh_b : Whh_f;
    float* hout      = dir ? hb : hf;

    const int t = threadIdx.x;
    const int lane = t & 63;
    const int wid = t >> 6;                       // wave id 0..15

    // stage f16 weights: uint2 slot i = col*50+l holds Whh[row(col)][4l..4l+3]
    // col = gate*25+unit -> row = gate*200 + sl*25 + unit.
    // Slots [5000,5064): ZEROED (lane>=50 over-reads must be finite — r15).
    for (int i = t; i < 5064; i += 1024) {
        uint2 v = {0u, 0u};
        if (i < 5000) {
            int col = i / 50, l = i - col * 50;
            int row = (col / 25) * 200 + sl * 25 + (col % 25);
            float4 w = *(const float4*)(Whh + (size_t)row * HD + 4 * l);
            h2_t p0; p0[0] = (_Float16)w.x; p0[1] = (_Float16)w.y;
            h2_t p1; p1[0] = (_Float16)w.z; p1[1] = (_Float16)w.w;
            v.x = __builtin_bit_cast(unsigned, p0);
            v.y = __builtin_bit_cast(unsigned, p1);
        }
        wlds16[i] = v;
    }
    if (t < 256) { h16A[t] = (_Float16)0.f; h16B[t] = (_Float16)0.f; }

    const bool is_act = (t >= 960) && (t < 985);  // wave 15, lanes 0..24
    const int u = t - 960;
    const bool fill = (t < 200) && (t / 25 != sl);
    float cstA = 0.f, cstB = 0.f;
    float xA0=0,xA1=0,xA2=0,xA3=0, xB0=0,xB1=0,xB2=0,xB3=0;
    if (is_act) {
        int ts0 = dir ? (S - 1) : 0;
        const float* pa = xg + ((size_t)bA * S + ts0) * G4 + sl * 25 + u;
        const float* pb = xg + ((size_t)bB * S + ts0) * G4 + sl * 25 + u;
        xA0 = pa[0]; xA1 = pa[200]; xA2 = pa[400]; xA3 = pa[600];
        xB0 = pb[0]; xB1 = pb[200]; xB2 = pb[400]; xB3 = pb[600];
    }
    __syncthreads();

    // per column: 1 ds_read_b64 (4 f16) + 2 v_dot2_f32_f16 + DPP reduce.
#define COMPUTE(h16X, gbX)                                                     \
    {                                                                          \
        uint2 hv = ((const uint2*)h16X)[lane];                                 \
        _Pragma("unroll")                                                      \
        for (int j = 0; j < 7; j++) {                                          \
            int c = wid + 15 * j;                                              \
            if (c < 100) {                                                     \
                uint2 wv = wlds16[c * 50 + lane];                              \
                float a = dot2f(wv.y, hv.y, dot2f(wv.x, hv.x, 0.f));           \
                a = wave_sum64(a);                                             \
                if (lane == 63) gbX[c] = a;                                    \
            }                                                                  \
        }                                                                      \
    }

#define POLL(dst, srcp)                                                        \
    {                                                                          \
        float v_;                                                              \
        do { v_ = __hip_atomic_load(srcp, __ATOMIC_RELAXED,                    \
                                    __HIP_MEMORY_SCOPE_AGENT); } while (v_ != v_); \
        dst = (_Float16)v_;                                                    \
    }

    for (int s = 0; s < S; s++) {
        const int ts  = dir ? (S - 1 - s) : s;          // time of step s
        const int tsp = dir ? (S - s)     : (s - 1);    // time of step s-1
        const int tsn = (s + 1 < S) ? (dir ? (S - 2 - s) : (s + 1)) : ts;

        // ======== SP0: act B(s-1) | compute A(s) | fill h16B <- h_B(s-1) ===
        if (is_act && s > 0) {
            float ig = fsig(gbB[u] + xB0);
            float fg = fsig(gbB[25 + u] + xB1);
            float gt = ftanh(gbB[50 + u] + xB2);
            float og = fsig(gbB[75 + u] + xB3);
            cstB = fg * cstB + ig * gt;
            float h = og * ftanh(cstB);
            h16B[sl * 25 + u] = (_Float16)h;
            __hip_atomic_store(&hout[((size_t)bB * S + tsp) * HD + sl * 25 + u], h,
                               __ATOMIC_RELAXED, __HIP_MEMORY_SCOPE_AGENT);
            const float* pn = xg + ((size_t)bB * S + ts) * G4 + sl * 25 + u;
            xB0 = pn[0]; xB1 = pn[200]; xB2 = pn[400]; xB3 = pn[600];
        }
        if (wid < 15) COMPUTE(h16A, gbA)
        if (s > 0 && fill) POLL(h16B[t], hout + ((size_t)bB * S + tsp) * HD + t)
        __syncthreads();

        // ======== SP1: act A(s) | compute B(s) | fill h16A <- h_A(s) =======
        if (is_act) {
            float ig = fsig(gbA[u] + xA0);
            float fg = fsig(gbA[25 + u] + xA1);
            float gt = ftanh(gbA[50 + u] + xA2);
            float og = fsig(gbA[75 + u] + xA3);
            cstA = fg * cstA + ig * gt;
            float h = og * ftanh(cstA);
            h16A[sl * 25 + u] = (_Float16)h;
            __hip_atomic_store(&hout[((size_t)bA * S + ts) * HD + sl * 25 + u], h,
                               __ATOMIC_RELAXED, __HIP_MEMORY_SCOPE_AGENT);
            const float* pn = xg + ((size_t)bA * S + tsn) * G4 + sl * 25 + u;
            xA0 = pn[0]; xA1 = pn[200]; xA2 = pn[400]; xA3 = pn[600];
        }
        if (wid < 15) COMPUTE(h16B, gbB)
        if (fill) POLL(h16A[t], hout + ((size_t)bA * S + ts) * HD + t)
        __syncthreads();
    }
    // epilogue: act B(S-1) (gbB from SP1(S-1), xB prefetched in SP0(S-1))
    if (is_act) {
        const int tl = dir ? 0 : (S - 1);
        float ig = fsig(gbB[u] + xB0);
        float fg = fsig(gbB[25 + u] + xB1);
        float gt = ftanh(gbB[50 + u] + xB2);
        float og = fsig(gbB[75 + u] + xB3);
        cstB = fg * cstB + ig * gt;
        float h = og * ftanh(cstB);
        __hip_atomic_store(&hout[((size_t)bB * S + tl) * HD + sl * 25 + u], h,
                           __ATOMIC_RELAXED, __HIP_MEMORY_SCOPE_AGENT);
    }
#undef COMPUTE
#undef POLL
}

// ---------------- K4: span features + subword emb + FFN ----------------
__global__ void out_k(const int* __restrict__ subwords,
                      const float* __restrict__ pre_w, const float* __restrict__ sub_w,
                      const float* __restrict__ hf, const float* __restrict__ hb,
                      const float* __restrict__ ffn_w, const float* __restrict__ ffn_b,
                      float* __restrict__ out) {
    int wave = (blockIdx.x * 256 + threadIdx.x) >> 6;
    int lane = threadIdx.x & 63;
    if (wave >= B * SK * W) return;
    int i = wave % W;
    int bk = wave / W;
    int k = bk % SK;
    int b = bk / SK;
    int end = k + i;
    float vscale = (end <= S - 3) ? 1.f : 0.f;
    int e1 = min(end + 1, S - 1);
    int e2 = min(end + 2, S - 1);
    const float* hfb = hf + (size_t)b * S * HD;
    const float* hbb = hb + (size_t)b * S * HD;
    int sw = subwords[wave];
    int sw2 = (sw >= SUBV) ? UNK : sw;
    float acc0 = 0, acc1 = 0, acc2 = 0, acc3 = 0;
    for (int j = lane; j < FEAT; j += 64) {
        float fv;
        if (j < HD) {
            fv = (hfb[(size_t)e1 * HD + j] - hfb[(size_t)k * HD + j]) * vscale;
        } else if (j < 2 * HD) {
            int jj = j - HD;
            fv = (hbb[(size_t)(k + 1) * HD + jj] - hbb[(size_t)e2 * HD + jj]) * vscale;
        } else {
            int jj = j - 2 * HD;
            fv = pre_w[(size_t)sw * SE + jj] + sub_w[(size_t)sw2 * SE + jj];
        }
        acc0 += ffn_w[j] * fv;
        acc1 += ffn_w[FEAT + j] * fv;
        acc2 += ffn_w[2 * FEAT + j] * fv;
        acc3 += ffn_w[3 * FEAT + j] * fv;
    }
    for (int off = 32; off; off >>= 1) {
        acc0 += __shfl_down(acc0, off);
        acc1 += __shfl_down(acc1, off);
        acc2 += __shfl_down(acc2, off);
        acc3 += __shfl_down(acc3, off);
    }
    if (lane == 0) {
        float* o = out + (size_t)wave * NL;
        o[0] = acc0 + ffn_b[0];
        o[1] = acc1 + ffn_b[1];
        o[2] = acc2 + ffn_b[2];
        o[3] = acc3 + ffn_b[3];
    }
}

extern "C" void kernel_launch(void* const* d_in, const int* in_sizes, int n_in,
                              void* d_out, int out_size, void* d_ws, size_t ws_size,
                              hipStream_t stream) {
    const int*   chars    = (const int*)d_in[0];
    const int*   bichars  = (const int*)d_in[1];
    const int*   subwords = (const int*)d_in[2];
    const float* cw    = (const float*)d_in[3];
    const float* bw    = (const float*)d_in[4];
    const float* subw  = (const float*)d_in[5];
    const float* prew  = (const float*)d_in[6];
    const float* Wih_f = (const float*)d_in[7];
    const float* Whh_f = (const float*)d_in[8];
    const float* b_f   = (const float*)d_in[9];
    const float* Wih_b = (const float*)d_in[10];
    const float* Whh_b = (const float*)d_in[11];
    const float* b_b   = (const float*)d_in[12];
    const float* ffn_w = (const float*)d_in[13];
    const float* ffn_b = (const float*)d_in[14];
    float* out = (float*)d_out;

    float* ws = (float*)d_ws;
    unsigned* WTh_f = (unsigned*)ws;         // 80000 u32 each (packed f16)
    unsigned* WTh_b = WTh_f + 80000;
    float* xgf = (float*)(WTh_b + 80000);    // 13,107,200
    float* xgb = xgf + 13107200;             // 13,107,200
    float* hf  = xgb + 13107200;             // 3,276,800
    float* hb  = hf + 3276800;               // 3,276,800 (contiguous with hf)

    // NaN-fill h buffers (one fused memset: hf|hb contiguous) — the data
    // word itself is the readiness flag for the lstm spin-sync.
    (void)hipMemsetAsync(hf, 0xFF, 2 * 3276800 * sizeof(float), stream);
    transpose_pack_k<<<313, 256, 0, stream>>>(Wih_f, WTh_f);
    transpose_pack_k<<<313, 256, 0, stream>>>(Wih_b, WTh_b);
    xg_k<<<dim3(B * S / 16, 2), 256, 0, stream>>>(chars, bichars, cw, bw,
                                                  WTh_f, b_f, WTh_b, b_b, xgf, xgb);
    lstm_k<<<256, 1024, 0, stream>>>(xgf, xgb, Whh_f, Whh_b, hf, hb);
    out_k<<<(B * SK * W) / 4, 256, 0, stream>>>(subwords, prew, subw, hf, hb, ffn_w, ffn_b, out);
}

// Round 22
// 1099.414 us; speedup vs baseline: 1.4367x; 1.0561x over previous
//
#include <hip/hip_runtime.h>
#include <hip/hip_bf16.h>
#include <math.h>

#define B 32
#define S 512
#define W 8
#define CE 100       // CHAR_EMB
#define SE 100       // SUB_EMB
#define HD 200       // hidden per direction
#define G4 800       // 4*HD
#define IN2 200      // 2*CHAR_EMB
#define SUBV 100000
#define UNK 1
#define NL 4
#define SK (S - 2)   // 510
#define FEAT 500     // 2*HD + SE

typedef _Float16 h2_t __attribute__((ext_vector_type(2)));

__device__ __forceinline__ float fsig(float x) {
    return 1.f / (1.f + __expf(-x));
}
__device__ __forceinline__ float ftanh(float x) {
    float e = __expf(-2.f * fabsf(x));   // e in (0,1], overflow-safe
    float r = (1.f - e) / (1.f + e);
    return copysignf(r, x);
}

// 64-lane sum; result valid in lane 63. DPP adds run on the VALU pipe.
__device__ __forceinline__ float wave_sum64(float v) {
#if __has_builtin(__builtin_amdgcn_update_dpp)
#define DPPADD(C) { int x_ = __builtin_amdgcn_update_dpp(0, __float_as_int(v), C, 0xf, 0xf, true); \
                    v += __int_as_float(x_); }
    DPPADD(0x111)  // row_shr:1
    DPPADD(0x112)  // row_shr:2
    DPPADD(0x114)  // row_shr:4
    DPPADD(0x118)  // row_shr:8  -> lane15/31/47/63 hold row sums
    DPPADD(0x142)  // row_bcast15 -> lane31 = rows0+1, lane63 = rows2+3
    DPPADD(0x143)  // row_bcast31 -> lane63 = total
#undef DPPADD
    return v;
#else
    v += __shfl_xor(v, 1);  v += __shfl_xor(v, 2);  v += __shfl_xor(v, 4);
    v += __shfl_xor(v, 8);  v += __shfl_xor(v, 16); v += __shfl_xor(v, 32);
    return v;
#endif
}

// packed-f16 2-way dot with f32 accumulate (v_dot2_f32_f16)
__device__ __forceinline__ float dot2f(unsigned a, unsigned b, float c) {
#if __has_builtin(__builtin_amdgcn_fdot2)
    return __builtin_amdgcn_fdot2(__builtin_bit_cast(h2_t, a),
                                  __builtin_bit_cast(h2_t, b), c, false);
#else
    h2_t x = __builtin_bit_cast(h2_t, a);
    h2_t y = __builtin_bit_cast(h2_t, b);
    return c + (float)x[0] * (float)y[0] + (float)x[1] * (float)y[1];
#endif
}

// -- K0: fused transpose+pack f16 for BOTH directions: Wih -> WTh[100][800]
__global__ void transpose_pack2_k(const float* __restrict__ inf, const float* __restrict__ inb,
                                  unsigned* __restrict__ outf, unsigned* __restrict__ outb) {
    int o = blockIdx.x * 256 + threadIdx.x;   // 160000 slots (2 x 80000)
    if (o >= 2 * 100 * G4) return;
    const float* in = (o < 100 * G4) ? inf : inb;
    unsigned* out   = (o < 100 * G4) ? outf : outb;
    int oo = (o < 100 * G4) ? o : o - 100 * G4;
    int k2 = oo / G4, g = oo % G4;
    h2_t v;
    v[0] = (_Float16)in[g * 200 + 2 * k2];
    v[1] = (_Float16)in[g * 200 + 2 * k2 + 1];
    out[oo] = __builtin_bit_cast(unsigned, v);
}

// ---------------- K2: fused embed + xg via v_dot2_f32_f16 ----------------
__global__ void xg_k(const int* __restrict__ chars, const int* __restrict__ bichars,
                     const float* __restrict__ cw, const float* __restrict__ bw,
                     const unsigned* __restrict__ WTh_f, const float* __restrict__ bf,
                     const unsigned* __restrict__ WTh_b, const float* __restrict__ bb,
                     float* __restrict__ xgf, float* __restrict__ xgb) {
    const int dir = blockIdx.y;
    const unsigned* WT = dir ? WTh_b : WTh_f;
    const float* bias  = dir ? bb : bf;
    float* out         = dir ? xgb : xgf;
    int r0 = blockIdx.x * 16;
    __shared__ unsigned xs2[16][100];
    for (int i = threadIdx.x; i < 16 * 100; i += 256) {
        int r = i / 100, c2 = i % 100;
        int row = r0 + r;                         // flat token index b*S+s
        float a, b;
        if (c2 < 50) {
            const float* p = cw + (size_t)chars[row] * CE + 2 * c2;
            a = p[0]; b = p[1];
        } else {
            const float* p = bw + (size_t)bichars[row] * CE + 2 * (c2 - 50);
            a = p[0]; b = p[1];
        }
        h2_t v; v[0] = (_Float16)a; v[1] = (_Float16)b;
        xs2[r][c2] = __builtin_bit_cast(unsigned, v);
    }
    __syncthreads();
    float acc[4][16];
    for (int q = 0; q < 4; q++)
        for (int r = 0; r < 16; r++) acc[q][r] = 0.f;
    int tid = threadIdx.x;
    for (int k2 = 0; k2 < 100; k2++) {
        const unsigned* wrow = WT + (size_t)k2 * G4;
        unsigned w0 = wrow[tid];
        unsigned w1 = wrow[tid + 256];
        unsigned w2 = wrow[tid + 512];
        unsigned w3 = (tid < 32) ? wrow[tid + 768] : 0u;
        for (int r = 0; r < 16; r++) {
            unsigned xv = xs2[r][k2];
            acc[0][r] = dot2f(w0, xv, acc[0][r]);
            acc[1][r] = dot2f(w1, xv, acc[1][r]);
            acc[2][r] = dot2f(w2, xv, acc[2][r]);
            acc[3][r] = dot2f(w3, xv, acc[3][r]);
        }
    }
    for (int q = 0; q < 4; q++) {
        int g = tid + q * 256;
        if (g < G4) {
            float bv = bias[g];
            for (int r = 0; r < 16; r++)
                out[(size_t)(r0 + r) * G4 + g] = acc[q][r] + bv;
        }
    }
}

// ---------------- K3: LSTM recurrence, f16-packed weights + h ------------
// FROZEN r21 structure (933us proven): r13 schedule (2 superphases/step,
// 1 barrier each: act-first -> compute -> fill-poll; staggered A/B) with
// Whh + h working copy in LDS as packed f16: per column 1 ds_read_b64 +
// 2 v_dot2_f32_f16 (f32 accum). h stays f32 in hout (sync protocol
// unchanged). All over-readable LDS zero-filled (r15); single genuinely-
// used 86KB LDS array pins 1 block/CU (r19/r14 lessons).
__global__ __launch_bounds__(1024)
void lstm_k(const float* __restrict__ xgf, const float* __restrict__ xgb,
            const float* __restrict__ Whh_f, const float* __restrict__ Whh_b,
            float* __restrict__ hf, float* __restrict__ hb) {
    __shared__ __align__(16) float lds_all[21504];   // 86016 B -> 1 block/CU
    uint2*    wlds16 = (uint2*)lds_all;              // 5064 uint2 (f16x4 each)
    _Float16* h16A = (_Float16*)(lds_all + 10240);   // 256 f16
    _Float16* h16B = (_Float16*)(lds_all + 10368);   // 256 f16
    float*    gbA  = lds_all + 10496;                // 112 f32
    float*    gbB  = lds_all + 10608;                // 112 f32

    const int blk = blockIdx.x;
    const int sl  = blk >> 5;                     // slice 0..7 (25 units)
    const int pg  = blk & 31;                     // dir*16 + pair; XCD = pg%8
    const int dir = pg >> 4;
    const int bA  = pg & 15;
    const int bB  = bA + 16;
    const float* xg  = dir ? xgb : xgf;
    const float* Whh = dir ? Whh_b : Whh_f;
    float* hout      = dir ? hb : hf;

    const int t = threadIdx.x;
    const int lane = t & 63;
    const int wid = t >> 6;                       // wave id 0..15

    for (int i = t; i < 5064; i += 1024) {
        uint2 v = {0u, 0u};
        if (i < 5000) {
            int col = i / 50, l = i - col * 50;
            int row = (col / 25) * 200 + sl * 25 + (col % 25);
            float4 w = *(const float4*)(Whh + (size_t)row * HD + 4 * l);
            h2_t p0; p0[0] = (_Float16)w.x; p0[1] = (_Float16)w.y;
            h2_t p1; p1[0] = (_Float16)w.z; p1[1] = (_Float16)w.w;
            v.x = __builtin_bit_cast(unsigned, p0);
            v.y = __builtin_bit_cast(unsigned, p1);
        }
        wlds16[i] = v;
    }
    if (t < 256) { h16A[t] = (_Float16)0.f; h16B[t] = (_Float16)0.f; }

    const bool is_act = (t >= 960) && (t < 985);  // wave 15, lanes 0..24
    const int u = t - 960;
    const bool fill = (t < 200) && (t / 25 != sl);
    float cstA = 0.f, cstB = 0.f;
    float xA0=0,xA1=0,xA2=0,xA3=0, xB0=0,xB1=0,xB2=0,xB3=0;
    if (is_act) {
        int ts0 = dir ? (S - 1) : 0;
        const float* pa = xg + ((size_t)bA * S + ts0) * G4 + sl * 25 + u;
        const float* pb = xg + ((size_t)bB * S + ts0) * G4 + sl * 25 + u;
        xA0 = pa[0]; xA1 = pa[200]; xA2 = pa[400]; xA3 = pa[600];
        xB0 = pb[0]; xB1 = pb[200]; xB2 = pb[400]; xB3 = pb[600];
    }
    __syncthreads();

#define COMPUTE(h16X, gbX)                                                     \
    {                                                                          \
        uint2 hv = ((const uint2*)h16X)[lane];                                 \
        _Pragma("unroll")                                                      \
        for (int j = 0; j < 7; j++) {                                          \
            int c = wid + 15 * j;                                              \
            if (c < 100) {                                                     \
                uint2 wv = wlds16[c * 50 + lane];                              \
                float a = dot2f(wv.y, hv.y, dot2f(wv.x, hv.x, 0.f));           \
                a = wave_sum64(a);                                             \
                if (lane == 63) gbX[c] = a;                                    \
            }                                                                  \
        }                                                                      \
    }

#define POLL(dst, srcp)                                                        \
    {                                                                          \
        float v_;                                                              \
        do { v_ = __hip_atomic_load(srcp, __ATOMIC_RELAXED,                    \
                                    __HIP_MEMORY_SCOPE_AGENT); } while (v_ != v_); \
        dst = (_Float16)v_;                                                    \
    }

    for (int s = 0; s < S; s++) {
        const int ts  = dir ? (S - 1 - s) : s;          // time of step s
        const int tsp = dir ? (S - s)     : (s - 1);    // time of step s-1
        const int tsn = (s + 1 < S) ? (dir ? (S - 2 - s) : (s + 1)) : ts;

        // ======== SP0: act B(s-1) | compute A(s) | fill h16B <- h_B(s-1) ===
        if (is_act && s > 0) {
            float ig = fsig(gbB[u] + xB0);
            float fg = fsig(gbB[25 + u] + xB1);
            float gt = ftanh(gbB[50 + u] + xB2);
            float og = fsig(gbB[75 + u] + xB3);
            cstB = fg * cstB + ig * gt;
            float h = og * ftanh(cstB);
            h16B[sl * 25 + u] = (_Float16)h;
            __hip_atomic_store(&hout[((size_t)bB * S + tsp) * HD + sl * 25 + u], h,
                               __ATOMIC_RELAXED, __HIP_MEMORY_SCOPE_AGENT);
            const float* pn = xg + ((size_t)bB * S + ts) * G4 + sl * 25 + u;
            xB0 = pn[0]; xB1 = pn[200]; xB2 = pn[400]; xB3 = pn[600];
        }
        if (wid < 15) COMPUTE(h16A, gbA)
        if (s > 0 && fill) POLL(h16B[t], hout + ((size_t)bB * S + tsp) * HD + t)
        __syncthreads();

        // ======== SP1: act A(s) | compute B(s) | fill h16A <- h_A(s) =======
        if (is_act) {
            float ig = fsig(gbA[u] + xA0);
            float fg = fsig(gbA[25 + u] + xA1);
            float gt = ftanh(gbA[50 + u] + xA2);
            float og = fsig(gbA[75 + u] + xA3);
            cstA = fg * cstA + ig * gt;
            float h = og * ftanh(cstA);
            h16A[sl * 25 + u] = (_Float16)h;
            __hip_atomic_store(&hout[((size_t)bA * S + ts) * HD + sl * 25 + u], h,
                               __ATOMIC_RELAXED, __HIP_MEMORY_SCOPE_AGENT);
            const float* pn = xg + ((size_t)bA * S + tsn) * G4 + sl * 25 + u;
            xA0 = pn[0]; xA1 = pn[200]; xA2 = pn[400]; xA3 = pn[600];
        }
        if (wid < 15) COMPUTE(h16B, gbB)
        if (fill) POLL(h16A[t], hout + ((size_t)bA * S + ts) * HD + t)
        __syncthreads();
    }
    // epilogue: act B(S-1)
    if (is_act) {
        const int tl = dir ? 0 : (S - 1);
        float ig = fsig(gbB[u] + xB0);
        float fg = fsig(gbB[25 + u] + xB1);
        float gt = ftanh(gbB[50 + u] + xB2);
        float og = fsig(gbB[75 + u] + xB3);
        cstB = fg * cstB + ig * gt;
        float h = og * ftanh(cstB);
        __hip_atomic_store(&hout[((size_t)bB * S + tl) * HD + sl * 25 + u], h,
                           __ATOMIC_RELAXED, __HIP_MEMORY_SCOPE_AGENT);
    }
#undef COMPUTE
#undef POLL
}

// ---------------- K4: span features + subword emb + FFN (v2) -------------
// One wave per (b,k), looping all 8 span lengths i. Hoisted per wave:
// hf[k] row, hb[k+1] row, and all ffn_w values (shared across the 8 i's) —
// cuts ~35-40% of out-phase memory traffic vs one-wave-per-(b,k,i).
__global__ void out_k(const int* __restrict__ subwords,
                      const float* __restrict__ pre_w, const float* __restrict__ sub_w,
                      const float* __restrict__ hf, const float* __restrict__ hb,
                      const float* __restrict__ ffn_w, const float* __restrict__ ffn_b,
                      float* __restrict__ out) {
    int wave = (blockIdx.x * 256 + threadIdx.x) >> 6;   // 0..B*SK-1
    int lane = threadIdx.x & 63;
    if (wave >= B * SK) return;
    int k = wave % SK;
    int b = wave / SK;
    const float* hfb = hf + (size_t)b * S * HD;
    const float* hbb = hb + (size_t)b * S * HD;

    // hoists: ffn rows (per-lane j = lane + 64*sl), hf[k], hb[k+1]
    float fw0[8], fw1[8], fw2[8], fw3[8];
    #pragma unroll
    for (int sl = 0; sl < 8; sl++) {
        int j = lane + 64 * sl;
        if (j < FEAT) {
            fw0[sl] = ffn_w[j];
            fw1[sl] = ffn_w[FEAT + j];
            fw2[sl] = ffn_w[2 * FEAT + j];
            fw3[sl] = ffn_w[3 * FEAT + j];
        } else { fw0[sl] = fw1[sl] = fw2[sl] = fw3[sl] = 0.f; }
    }
    float hfk[4];
    #pragma unroll
    for (int sl = 0; sl < 4; sl++) {
        int j = lane + 64 * sl;
        hfk[sl] = (j < HD) ? hfb[(size_t)k * HD + j] : 0.f;
    }
    float hbk1[4];
    #pragma unroll
    for (int sl = 3; sl < 7; sl++) {
        int j = lane + 64 * sl;
        hbk1[sl - 3] = (j >= HD && j < 2 * HD) ? hbb[(size_t)(k + 1) * HD + (j - HD)] : 0.f;
    }

    const int swbase = wave * W;
    float b0 = ffn_b[0], b1 = ffn_b[1], b2 = ffn_b[2], b3 = ffn_b[3];
    #pragma unroll
    for (int i = 0; i < W; i++) {
        int end = k + i;
        float vs = (end <= S - 3) ? 1.f : 0.f;
        int e1 = min(end + 1, S - 1);
        int e2 = min(end + 2, S - 1);
        int sw = subwords[swbase + i];
        int sw2 = (sw >= SUBV) ? UNK : sw;
        float a0 = 0, a1 = 0, a2 = 0, a3 = 0;
        #pragma unroll
        for (int sl = 0; sl < 8; sl++) {
            int j = lane + 64 * sl;
            float fv;
            if (j < HD) {
                fv = (hfb[(size_t)e1 * HD + j] - hfk[sl]) * vs;
            } else if (j < 2 * HD) {
                fv = (hbk1[sl - 3] - hbb[(size_t)e2 * HD + (j - HD)]) * vs;
            } else if (j < FEAT) {
                int jj = j - 2 * HD;
                fv = pre_w[(size_t)sw * SE + jj] + sub_w[(size_t)sw2 * SE + jj];
            } else {
                fv = 0.f;
            }
            a0 = fmaf(fw0[sl], fv, a0);
            a1 = fmaf(fw1[sl], fv, a1);
            a2 = fmaf(fw2[sl], fv, a2);
            a3 = fmaf(fw3[sl], fv, a3);
        }
        for (int off = 32; off; off >>= 1) {
            a0 += __shfl_down(a0, off);
            a1 += __shfl_down(a1, off);
            a2 += __shfl_down(a2, off);
            a3 += __shfl_down(a3, off);
        }
        if (lane == 0) {
            float* o = out + (size_t)(swbase + i) * NL;
            o[0] = a0 + b0;
            o[1] = a1 + b1;
            o[2] = a2 + b2;
            o[3] = a3 + b3;
        }
    }
}

extern "C" void kernel_launch(void* const* d_in, const int* in_sizes, int n_in,
                              void* d_out, int out_size, void* d_ws, size_t ws_size,
                              hipStream_t stream) {
    const int*   chars    = (const int*)d_in[0];
    const int*   bichars  = (const int*)d_in[1];
    const int*   subwords = (const int*)d_in[2];
    const float* cw    = (const float*)d_in[3];
    const float* bw    = (const float*)d_in[4];
    const float* subw  = (const float*)d_in[5];
    const float* prew  = (const float*)d_in[6];
    const float* Wih_f = (const float*)d_in[7];
    const float* Whh_f = (const float*)d_in[8];
    const float* b_f   = (const float*)d_in[9];
    const float* Wih_b = (const float*)d_in[10];
    const float* Whh_b = (const float*)d_in[11];
    const float* b_b   = (const float*)d_in[12];
    const float* ffn_w = (const float*)d_in[13];
    const float* ffn_b = (const float*)d_in[14];
    float* out = (float*)d_out;

    float* ws = (float*)d_ws;
    unsigned* WTh_f = (unsigned*)ws;         // 80000 u32 each (packed f16)
    unsigned* WTh_b = WTh_f + 80000;
    float* xgf = (float*)(WTh_b + 80000);    // 13,107,200
    float* xgb = xgf + 13107200;             // 13,107,200
    float* hf  = xgb + 13107200;             // 3,276,800
    float* hb  = hf + 3276800;               // 3,276,800 (contiguous with hf)

    // NaN-fill h buffers (fused memset: hf|hb contiguous) — the data word
    // itself is the readiness flag for the lstm spin-sync.
    (void)hipMemsetAsync(hf, 0xFF, 2 * 3276800 * sizeof(float), stream);
    transpose_pack2_k<<<625, 256, 0, stream>>>(Wih_f, Wih_b, WTh_f, WTh_b);
    xg_k<<<dim3(B * S / 16, 2), 256, 0, stream>>>(chars, bichars, cw, bw,
                                                  WTh_f, b_f, WTh_b, b_b, xgf, xgb);
    lstm_k<<<256, 1024, 0, stream>>>(xgf, xgb, Whh_f, Whh_b, hf, hb);
    out_k<<<(B * SK + 3) / 4, 256, 0, stream>>>(subwords, prew, subw, hf, hb, ffn_w, ffn_b, out);
}